// Round 5
// baseline (251.921 us; speedup 1.0000x reference)
//
#include <hip/hip_runtime.h>
#include <hip/hip_bf16.h>

// HumanVAttention: QKV proj (+fused V-transpose) -> in-place RoPE -> GQA block-sparse attn -> out proj
// B=1 S=4096 HID=2048 NH=16 NKV=4 HD=128 BLK=64 LOCAL=4 GNB=2 STRIDE=4 ROT=64

typedef short short8 __attribute__((ext_vector_type(8)));
typedef short s16x4  __attribute__((ext_vector_type(4)));
typedef float f32x4  __attribute__((ext_vector_type(4)));

#define NEGV   (-1.0e9f)
#define SCALE  (0.08838834764831845f)

__device__ __forceinline__ void gload16(const void* g, void* l) {
  __builtin_amdgcn_global_load_lds(
      (const __attribute__((address_space(1))) unsigned int*)g,
      (__attribute__((address_space(3))) unsigned int*)l, 16, 0, 0);
}

__device__ __forceinline__ float bf2f(short s) {
  union { unsigned u; float f; } c;
  c.u = ((unsigned)(unsigned short)s) << 16;
  return c.f;
}

__device__ __forceinline__ short f2bf_s(float f) {
  __hip_bfloat16 b = __float2bfloat16(f);
  short s;
  __builtin_memcpy(&s, &b, 2);
  return s;
}

// ---------------- elementwise convert hidden f32 -> bf16 ----------------
__global__ void conv_hidden(const float* __restrict__ H, __hip_bfloat16* __restrict__ X) {
  size_t t = (size_t)blockIdx.x * 256 + threadIdx.x;   // one float4 per thread
  float4 v = *(const float4*)(H + t * 4);
  __hip_bfloat16* o = X + t * 4;
  o[0] = __float2bfloat16(v.x); o[1] = __float2bfloat16(v.y);
  o[2] = __float2bfloat16(v.z); o[3] = __float2bfloat16(v.w);
}

// ---------------- tiled transpose f32[R][C] -> bf16 dst[C][R] ----------------
__global__ void transpose_f32_to_bf16(const float* __restrict__ src,
                                      __hip_bfloat16* __restrict__ dst,
                                      int R, int C) {
  __shared__ __hip_bfloat16 tile[64][73];
  int r0 = blockIdx.x * 64, c0 = blockIdx.y * 64;
  int c = threadIdx.x & 63, rq = threadIdx.x >> 6;
#pragma unroll
  for (int i = 0; i < 16; ++i) {
    int r = i * 4 + rq;
    tile[r][c] = __float2bfloat16(src[(size_t)(r0 + r) * C + c0 + c]);
  }
  __syncthreads();
#pragma unroll
  for (int i = 0; i < 16; ++i) {
    int cc = i * 4 + rq;
    dst[(size_t)(c0 + cc) * R + r0 + c] = tile[c][cc];
  }
}

// ---------------- in-place partial RoPE on Qb and Kb ----------------
// Each thread owns a (d, d+32) rotation pair group of 8: reads both, writes both (no race).
// grid: 4096*16*4 (Q) + 4096*4*4 (K) = 327680 threads = 1280 blocks.
__global__ void rope_inplace(const float* __restrict__ cosb, const float* __restrict__ sinb,
                             __hip_bfloat16* __restrict__ Qb, __hip_bfloat16* __restrict__ Kb) {
  int t = blockIdx.x * 256 + threadIdx.x;
  __hip_bfloat16* p;
  int s;
  if (t < 262144) {               // Q: s = t>>6, then 16 h x 4 g
    s = t >> 6;
    int rem = t & 63;
    p = Qb + (size_t)s * 2048 + (rem >> 2) * 128 + (rem & 3) * 8;
  } else {                        // K: s = tk>>4, then 4 h x 4 g
    int tk = t - 262144;
    s = tk >> 4;
    int rem = tk & 15;
    p = Kb + (size_t)s * 512 + (rem >> 2) * 128 + (rem & 3) * 8;
  }
  const int g8 = (t & 3) * 8;     // d offset in [0,32)
  const float* cp = cosb + (size_t)s * 64 + g8;
  const float* sp = sinb + (size_t)s * 64 + g8;
  short8 a = *(const short8*)p;          // x[d],    d in [0,32)
  short8 b = *(const short8*)(p + 32);   // x[d+32]
  float ca[8], sa[8], cb[8], sb[8];
  *(float4*)&ca[0] = *(const float4*)cp;        *(float4*)&ca[4] = *(const float4*)(cp + 4);
  *(float4*)&cb[0] = *(const float4*)(cp + 32); *(float4*)&cb[4] = *(const float4*)(cp + 36);
  *(float4*)&sa[0] = *(const float4*)sp;        *(float4*)&sa[4] = *(const float4*)(sp + 4);
  *(float4*)&sb[0] = *(const float4*)(sp + 32); *(float4*)&sb[4] = *(const float4*)(sp + 36);
  short8 oa, ob;
#pragma unroll
  for (int i = 0; i < 8; ++i) {
    float av = bf2f(a[i]), bv = bf2f(b[i]);
    oa[i] = f2bf_s(av * ca[i] - bv * sa[i]);   // rot_half: d<32 -> -x[d+32]
    ob[i] = f2bf_s(bv * cb[i] + av * sb[i]);   // d>=32   -> +x[d-32]
  }
  *(short8*)p = oa;
  *(short8*)(p + 32) = ob;
}

// ---------------- GEMM1: X[4096][2048] . Wt[3072][2048]^T, fused V-transpose epilogue ----------------
// 128x128 tile, BK=64, 256 threads (2x2 waves of 64x64), 16x16x32 MFMA.
// bn<16 -> Q head (plain store), 16..19 -> K head (plain store), 20..23 -> V (store transposed to Vt).
__global__ __launch_bounds__(256) void gemm_qkv(
    const __hip_bfloat16* __restrict__ A, const __hip_bfloat16* __restrict__ Bt,
    __hip_bfloat16* __restrict__ Qb, __hip_bfloat16* __restrict__ Kb,
    __hip_bfloat16* __restrict__ Vt) {
  const int K = 2048;
  const int tid = threadIdx.x;
  const int wave = tid >> 6, lane = tid & 63;
  const int l15 = lane & 15, lg = lane >> 4;
  const int bm = blockIdx.x, bn = blockIdx.y;
  const int wm = wave >> 1, wn = wave & 1;

  __shared__ __hip_bfloat16 As[128 * 64];
  __shared__ __hip_bfloat16 Bs[128 * 64];

  f32x4 acc[4][4] = {};
  const int lrow = lane >> 3;
  const int lslot = lane & 7;
  const int scol = (lslot ^ lrow) * 8;
  const size_t abase = (size_t)bm * 128 * K;
  const size_t bbase = (size_t)bn * 128 * K;
  const int r3 = l15 & 7;

  for (int k0 = 0; k0 < K; k0 += 64) {
#pragma unroll
    for (int i = 0; i < 4; ++i) {
      int seg = i * 4 + wave;
      int row = seg * 8 + lrow;
      gload16(A + abase + (size_t)row * K + k0 + scol, &As[seg * 512]);
      gload16(Bt + bbase + (size_t)row * K + k0 + scol, &Bs[seg * 512]);
    }
    __syncthreads();
#pragma unroll
    for (int ks = 0; ks < 2; ++ks) {
      const int slot = (ks * 4 + lg) ^ r3;
      short8 af[4], bf[4];
#pragma unroll
      for (int mi = 0; mi < 4; ++mi)
        af[mi] = *(const short8*)&As[(wm * 64 + mi * 16 + l15) * 64 + slot * 8];
#pragma unroll
      for (int ni = 0; ni < 4; ++ni)
        bf[ni] = *(const short8*)&Bs[(wn * 64 + ni * 16 + l15) * 64 + slot * 8];
#pragma unroll
      for (int mi = 0; mi < 4; ++mi)
#pragma unroll
        for (int ni = 0; ni < 4; ++ni)
          acc[mi][ni] = __builtin_amdgcn_mfma_f32_16x16x32_bf16(af[mi], bf[ni], acc[mi][ni], 0, 0, 0);
    }
    __syncthreads();
  }

  // ---- epilogue ----
  const int srow0 = bm * 128 + wm * 64;
  if (bn < 20) {
    __hip_bfloat16* dst; int ld;
    if (bn < 16) { dst = Qb + (size_t)bn * 128;        ld = 2048; }
    else         { dst = Kb + (size_t)(bn - 16) * 128; ld = 512;  }
#pragma unroll
    for (int mi = 0; mi < 4; ++mi)
#pragma unroll
      for (int ni = 0; ni < 4; ++ni) {
        int dcol = wn * 64 + ni * 16 + l15;
        int srow = srow0 + mi * 16 + lg * 4;
#pragma unroll
        for (int r = 0; r < 4; ++r)
          dst[(size_t)(srow + r) * ld + dcol] = __float2bfloat16(acc[mi][ni][r]);
      }
  } else {
    const int c0 = (bn - 20) * 128;
#pragma unroll
    for (int mi = 0; mi < 4; ++mi)
#pragma unroll
      for (int ni = 0; ni < 4; ++ni) {
        int c  = c0 + wn * 64 + ni * 16 + l15;
        int s0 = srow0 + mi * 16 + lg * 4;
        s16x4 o;
#pragma unroll
        for (int r = 0; r < 4; ++r) o[r] = f2bf_s(acc[mi][ni][r]);
        *(s16x4*)&Vt[(size_t)c * 4096 + s0] = o;   // transposed write, 8B/lane
      }
  }
}

// ---------------- GEMM2: C[M][N] f32 = A[M][K] bf16 . Bt[N][K]^T bf16 ----------------
__global__ __launch_bounds__(256) void gemm_bt(
    const __hip_bfloat16* __restrict__ A, const __hip_bfloat16* __restrict__ Bt,
    float* __restrict__ C, int M, int N, int K) {
  const int tid = threadIdx.x;
  const int wave = tid >> 6, lane = tid & 63;
  const int l15 = lane & 15, lg = lane >> 4;
  const int bm = blockIdx.x, bn = blockIdx.y;
  const int wm = wave >> 1, wn = wave & 1;

  __shared__ __hip_bfloat16 As[128 * 64];
  __shared__ __hip_bfloat16 Bs[128 * 64];

  f32x4 acc[4][4] = {};
  const int lrow = lane >> 3;
  const int lslot = lane & 7;
  const int scol = (lslot ^ lrow) * 8;
  const size_t abase = (size_t)bm * 128 * K;
  const size_t bbase = (size_t)bn * 128 * K;
  const int r3 = l15 & 7;

  for (int k0 = 0; k0 < K; k0 += 64) {
#pragma unroll
    for (int i = 0; i < 4; ++i) {
      int seg = i * 4 + wave;
      int row = seg * 8 + lrow;
      gload16(A + abase + (size_t)row * K + k0 + scol, &As[seg * 512]);
      gload16(Bt + bbase + (size_t)row * K + k0 + scol, &Bs[seg * 512]);
    }
    __syncthreads();
#pragma unroll
    for (int ks = 0; ks < 2; ++ks) {
      const int slot = (ks * 4 + lg) ^ r3;
      short8 af[4], bf[4];
#pragma unroll
      for (int mi = 0; mi < 4; ++mi)
        af[mi] = *(const short8*)&As[(wm * 64 + mi * 16 + l15) * 64 + slot * 8];
#pragma unroll
      for (int ni = 0; ni < 4; ++ni)
        bf[ni] = *(const short8*)&Bs[(wn * 64 + ni * 16 + l15) * 64 + slot * 8];
#pragma unroll
      for (int mi = 0; mi < 4; ++mi)
#pragma unroll
        for (int ni = 0; ni < 4; ++ni)
          acc[mi][ni] = __builtin_amdgcn_mfma_f32_16x16x32_bf16(af[mi], bf[ni], acc[mi][ni], 0, 0, 0);
    }
    __syncthreads();
  }
#pragma unroll
  for (int mi = 0; mi < 4; ++mi)
#pragma unroll
    for (int ni = 0; ni < 4; ++ni) {
      int row = bm * 128 + wm * 64 + mi * 16 + lg * 4;
      int col = bn * 128 + wn * 64 + ni * 16 + l15;
#pragma unroll
      for (int r = 0; r < 4; ++r)
        C[(size_t)(row + r) * N + col] = acc[mi][ni][r];
    }
}

// ---------------- block-sparse attention (barrier-free, K/V direct from global/L2) ----------------
// grid = nb*NH = 1024 blocks; block = 256 threads = 4 waves; wave w owns q-rows [w*16, w*16+16)
__global__ __launch_bounds__(256) void attn_kernel(
    const __hip_bfloat16* __restrict__ Qb,  // [4096][2048]
    const __hip_bfloat16* __restrict__ Kb,  // [4096][512]
    const __hip_bfloat16* __restrict__ Vt,  // [512][4096]  (channel-major)
    const float* __restrict__ amask,        // [4096]
    __hip_bfloat16* __restrict__ AO)        // [4096][2048]
{
  const int bid = blockIdx.x;
  const int h = bid & 15;
  const int bi = bid >> 4;
  const int kvh = h >> 2;
  const int tid = threadIdx.x;
  const int wave = tid >> 6, lane = tid & 63;
  const int l15 = lane & 15, lg = lane >> 4;

  // static block selection (matches _select_key_blocks): <=6 blocks
  int sel[6]; int nsel = 0;
  {
    int gtop = bi >> 2;
    for (int j = 0; j <= bi; ++j) {
      bool pick = (j == 0) || (j >= bi - 3) || (((j & 3) == 0) && ((j >> 2) >= gtop - 1));
      if (pick && nsel < 6) sel[nsel++] = j;
    }
  }

  __shared__ __hip_bfloat16 Pb[64 * 72];   // P tile, wave-private rows -> no barriers needed

  // Q fragments in registers (A operand, 4 k-steps of 32)
  short8 qf[4];
  {
    const __hip_bfloat16* qbase =
        Qb + (size_t)(bi * 64 + wave * 16 + l15) * 2048 + h * 128 + lg * 8;
#pragma unroll
    for (int ks = 0; ks < 4; ++ks) qf[ks] = *(const short8*)(qbase + ks * 32);
  }

  // ---- phase 1: scores, K fragments read directly from global (L2-resident) ----
  f32x4 sc[6][4] = {};
#pragma unroll
  for (int j = 0; j < 6; ++j) {
    if (j < nsel) {
      const __hip_bfloat16* kbase =
          Kb + (size_t)(sel[j] * 64) * 512 + kvh * 128;
#pragma unroll
      for (int nf = 0; nf < 4; ++nf)
#pragma unroll
        for (int ks = 0; ks < 4; ++ks) {
          short8 bfr = *(const short8*)(kbase + (size_t)(nf * 16 + l15) * 512 + ks * 32 + lg * 8);
          sc[j][nf] = __builtin_amdgcn_mfma_f32_16x16x32_bf16(qf[ks], bfr, sc[j][nf], 0, 0, 0);
        }
    }
  }

  // ---- phase 2: mask + softmax (rows live in (lg, r)) ----
  float rowmax[4] = {-3.0e38f, -3.0e38f, -3.0e38f, -3.0e38f};
#pragma unroll
  for (int j = 0; j < 6; ++j) {
    if (j >= nsel) continue;
    int kb = sel[j];
#pragma unroll
    for (int nf = 0; nf < 4; ++nf) {
      int keyg = kb * 64 + nf * 16 + l15;
      float mterm = (1.0f - amask[keyg]) * NEGV;
      int keyl = nf * 16 + l15;
#pragma unroll
      for (int r = 0; r < 4; ++r) {
        float s = sc[j][nf][r] * SCALE + mterm;
        if (kb == bi) {
          int qrow = wave * 16 + lg * 4 + r;
          if (keyl > qrow) s = NEGV;
        }
        sc[j][nf][r] = s;
        rowmax[r] = fmaxf(rowmax[r], s);
      }
    }
  }
#pragma unroll
  for (int r = 0; r < 4; ++r) {
    float v = rowmax[r];
    v = fmaxf(v, __shfl_xor(v, 1)); v = fmaxf(v, __shfl_xor(v, 2));
    v = fmaxf(v, __shfl_xor(v, 4)); v = fmaxf(v, __shfl_xor(v, 8));
    rowmax[r] = v;
  }
  float rinv[4] = {0.f, 0.f, 0.f, 0.f};
#pragma unroll
  for (int j = 0; j < 6; ++j) {
    if (j >= nsel) continue;
#pragma unroll
    for (int nf = 0; nf < 4; ++nf)
#pragma unroll
      for (int r = 0; r < 4; ++r) {
        float p = __expf(sc[j][nf][r] - rowmax[r]);
        sc[j][nf][r] = p;
        rinv[r] += p;
      }
  }
#pragma unroll
  for (int r = 0; r < 4; ++r) {
    float v = rinv[r];
    v += __shfl_xor(v, 1); v += __shfl_xor(v, 2);
    v += __shfl_xor(v, 4); v += __shfl_xor(v, 8);
    rinv[r] = 1.0f / v;
  }

  // ---- phase 3: PV, V fragments read directly from global (L2-resident) ----
  f32x4 oacc[8] = {};
#pragma unroll
  for (int j = 0; j < 6; ++j) {
    if (j < nsel) {
      int kb = sel[j];
      // write normalized P tile (wave-private rows; same-wave LDS ordering via lgkmcnt)
#pragma unroll
      for (int nf = 0; nf < 4; ++nf)
#pragma unroll
        for (int r = 0; r < 4; ++r) {
          int qrow = wave * 16 + lg * 4 + r;
          Pb[qrow * 72 + nf * 16 + l15] = __float2bfloat16(sc[j][nf][r] * rinv[r]);
        }
      const __hip_bfloat16* vbase = Vt + (size_t)(kvh * 128) * 4096 + kb * 64;
#pragma unroll
      for (int ks = 0; ks < 2; ++ks) {
        short8 pa = *(const short8*)&Pb[(wave * 16 + l15) * 72 + ks * 32 + lg * 8];
#pragma unroll
        for (int df = 0; df < 8; ++df) {
          short8 vb = *(const short8*)(vbase + (size_t)(df * 16 + l15) * 4096 + ks * 32 + lg * 8);
          oacc[df] = __builtin_amdgcn_mfma_f32_16x16x32_bf16(pa, vb, oacc[df], 0, 0, 0);
        }
      }
    }
  }

  // ---- phase 4: write AO ----
#pragma unroll
  for (int df = 0; df < 8; ++df)
#pragma unroll
    for (int r = 0; r < 4; ++r) {
      int qrow = bi * 64 + wave * 16 + lg * 4 + r;
      AO[(size_t)qrow * 2048 + h * 128 + df * 16 + l15] = __float2bfloat16(oacc[df][r]);
    }
}

// ---------------- launch ----------------
extern "C" void kernel_launch(void* const* d_in, const int* in_sizes, int n_in,
                              void* d_out, int out_size, void* d_ws, size_t ws_size,
                              hipStream_t stream) {
  const float* hidden = (const float*)d_in[0];
  const float* cosb   = (const float*)d_in[1];
  const float* sinb   = (const float*)d_in[2];
  const float* Wq     = (const float*)d_in[3];
  const float* Wk     = (const float*)d_in[4];
  const float* Wv     = (const float*)d_in[5];
  const float* Wo     = (const float*)d_in[6];
  const float* amask  = (const float*)d_in[7];

  char* ws = (char*)d_ws;
  __hip_bfloat16* Xb   = (__hip_bfloat16*)(ws);               // 16,777,216 B  [4096][2048]
  __hip_bfloat16* Wt   = (__hip_bfloat16*)(ws + 16777216);    // 12,582,912 B  [3072][2048]
  __hip_bfloat16* Wot  = (__hip_bfloat16*)(ws + 29360128);    //  8,388,608 B  [2048][2048]
  __hip_bfloat16* Qb   = (__hip_bfloat16*)(ws + 37748736);    // 16,777,216 B  [4096][2048]
  __hip_bfloat16* Kb   = (__hip_bfloat16*)(ws + 54525952);    //  4,194,304 B  [4096][512]
  __hip_bfloat16* Vt   = (__hip_bfloat16*)(ws + 58720256);    //  4,194,304 B  [512][4096]
  __hip_bfloat16* AO   = Xb;  // Xb dead after gemm_qkv; reuse for attention output

  conv_hidden<<<8192, 256, 0, stream>>>(hidden, Xb);
  transpose_f32_to_bf16<<<dim3(32, 32), 256, 0, stream>>>(Wq, Wt, 2048, 2048);
  transpose_f32_to_bf16<<<dim3(32, 8),  256, 0, stream>>>(Wk, Wt + (size_t)2048 * 2048, 2048, 512);
  transpose_f32_to_bf16<<<dim3(32, 8),  256, 0, stream>>>(Wv, Wt + (size_t)2560 * 2048, 2048, 512);
  transpose_f32_to_bf16<<<dim3(32, 32), 256, 0, stream>>>(Wo, Wot, 2048, 2048);

  gemm_qkv<<<dim3(32, 24), 256, 0, stream>>>(Xb, Wt, Qb, Kb, Vt);

  rope_inplace<<<1280, 256, 0, stream>>>(cosb, sinb, Qb, Kb);

  attn_kernel<<<1024, 256, 0, stream>>>(Qb, Kb, Vt, amask, AO);

  gemm_bt<<<dim3(32, 16), 256, 0, stream>>>(AO, Wot, (float*)d_out, 4096, 2048, 2048);
}

// Round 6
// 225.816 us; speedup vs baseline: 1.1156x; 1.1156x over previous
//
#include <hip/hip_runtime.h>
#include <hip/hip_bf16.h>

// HumanVAttention: QKV proj (+fused V-transpose) -> in-place RoPE -> GQA block-sparse attn -> out proj
// B=1 S=4096 HID=2048 NH=16 NKV=4 HD=128 BLK=64 LOCAL=4 GNB=2 STRIDE=4 ROT=64

typedef short short8 __attribute__((ext_vector_type(8)));
typedef short s16x4  __attribute__((ext_vector_type(4)));
typedef float f32x4  __attribute__((ext_vector_type(4)));

#define NEGV   (-1.0e9f)
#define SCALE  (0.08838834764831845f)

__device__ __forceinline__ void gload16(const void* g, void* l) {
  __builtin_amdgcn_global_load_lds(
      (const __attribute__((address_space(1))) unsigned int*)g,
      (__attribute__((address_space(3))) unsigned int*)l, 16, 0, 0);
}

__device__ __forceinline__ float bf2f(short s) {
  union { unsigned u; float f; } c;
  c.u = ((unsigned)(unsigned short)s) << 16;
  return c.f;
}

__device__ __forceinline__ short f2bf_s(float f) {
  __hip_bfloat16 b = __float2bfloat16(f);
  short s;
  __builtin_memcpy(&s, &b, 2);
  return s;
}

// ---------------- elementwise convert hidden f32 -> bf16 ----------------
__global__ void conv_hidden(const float* __restrict__ H, __hip_bfloat16* __restrict__ X) {
  size_t t = (size_t)blockIdx.x * 256 + threadIdx.x;   // one float4 per thread
  float4 v = *(const float4*)(H + t * 4);
  __hip_bfloat16* o = X + t * 4;
  o[0] = __float2bfloat16(v.x); o[1] = __float2bfloat16(v.y);
  o[2] = __float2bfloat16(v.z); o[3] = __float2bfloat16(v.w);
}

// ---------------- tiled transpose f32[R][C] -> bf16 dst[C][R] ----------------
__global__ void transpose_f32_to_bf16(const float* __restrict__ src,
                                      __hip_bfloat16* __restrict__ dst,
                                      int R, int C) {
  __shared__ __hip_bfloat16 tile[64][73];
  int r0 = blockIdx.x * 64, c0 = blockIdx.y * 64;
  int c = threadIdx.x & 63, rq = threadIdx.x >> 6;
#pragma unroll
  for (int i = 0; i < 16; ++i) {
    int r = i * 4 + rq;
    tile[r][c] = __float2bfloat16(src[(size_t)(r0 + r) * C + c0 + c]);
  }
  __syncthreads();
#pragma unroll
  for (int i = 0; i < 16; ++i) {
    int cc = i * 4 + rq;
    dst[(size_t)(c0 + cc) * R + r0 + c] = tile[c][cc];
  }
}

// ---------------- in-place partial RoPE on Qb and Kb ----------------
__global__ void rope_inplace(const float* __restrict__ cosb, const float* __restrict__ sinb,
                             __hip_bfloat16* __restrict__ Qb, __hip_bfloat16* __restrict__ Kb) {
  int t = blockIdx.x * 256 + threadIdx.x;
  __hip_bfloat16* p;
  int s;
  if (t < 262144) {               // Q: s = t>>6, then 16 h x 4 g
    s = t >> 6;
    int rem = t & 63;
    p = Qb + (size_t)s * 2048 + (rem >> 2) * 128 + (rem & 3) * 8;
  } else {                        // K: s = tk>>4, then 4 h x 4 g
    int tk = t - 262144;
    s = tk >> 4;
    int rem = tk & 15;
    p = Kb + (size_t)s * 512 + (rem >> 2) * 128 + (rem & 3) * 8;
  }
  const int g8 = (t & 3) * 8;     // d offset in [0,32)
  const float* cp = cosb + (size_t)s * 64 + g8;
  const float* sp = sinb + (size_t)s * 64 + g8;
  short8 a = *(const short8*)p;          // x[d],    d in [0,32)
  short8 b = *(const short8*)(p + 32);   // x[d+32]
  float ca[8], sa[8], cb[8], sb[8];
  *(float4*)&ca[0] = *(const float4*)cp;        *(float4*)&ca[4] = *(const float4*)(cp + 4);
  *(float4*)&cb[0] = *(const float4*)(cp + 32); *(float4*)&cb[4] = *(const float4*)(cp + 36);
  *(float4*)&sa[0] = *(const float4*)sp;        *(float4*)&sa[4] = *(const float4*)(sp + 4);
  *(float4*)&sb[0] = *(const float4*)(sp + 32); *(float4*)&sb[4] = *(const float4*)(sp + 36);
  short8 oa, ob;
#pragma unroll
  for (int i = 0; i < 8; ++i) {
    float av = bf2f(a[i]), bv = bf2f(b[i]);
    oa[i] = f2bf_s(av * ca[i] - bv * sa[i]);   // rot_half: d<32 -> -x[d+32]
    ob[i] = f2bf_s(bv * cb[i] + av * sb[i]);   // d>=32   -> +x[d-32]
  }
  *(short8*)p = oa;
  *(short8*)(p + 32) = ob;
}

// ---------------- GEMM1: X[4096][2048] . Wt[3072][2048]^T, fused V-transpose epilogue ----------------
__global__ __launch_bounds__(256) void gemm_qkv(
    const __hip_bfloat16* __restrict__ A, const __hip_bfloat16* __restrict__ Bt,
    __hip_bfloat16* __restrict__ Qb, __hip_bfloat16* __restrict__ Kb,
    __hip_bfloat16* __restrict__ Vt) {
  const int K = 2048;
  const int tid = threadIdx.x;
  const int wave = tid >> 6, lane = tid & 63;
  const int l15 = lane & 15, lg = lane >> 4;
  const int bm = blockIdx.x, bn = blockIdx.y;
  const int wm = wave >> 1, wn = wave & 1;

  __shared__ __hip_bfloat16 As[128 * 64];
  __shared__ __hip_bfloat16 Bs[128 * 64];

  f32x4 acc[4][4] = {};
  const int lrow = lane >> 3;
  const int lslot = lane & 7;
  const int scol = (lslot ^ lrow) * 8;
  const size_t abase = (size_t)bm * 128 * K;
  const size_t bbase = (size_t)bn * 128 * K;
  const int r3 = l15 & 7;

  for (int k0 = 0; k0 < K; k0 += 64) {
#pragma unroll
    for (int i = 0; i < 4; ++i) {
      int seg = i * 4 + wave;
      int row = seg * 8 + lrow;
      gload16(A + abase + (size_t)row * K + k0 + scol, &As[seg * 512]);
      gload16(Bt + bbase + (size_t)row * K + k0 + scol, &Bs[seg * 512]);
    }
    __syncthreads();
#pragma unroll
    for (int ks = 0; ks < 2; ++ks) {
      const int slot = (ks * 4 + lg) ^ r3;
      short8 af[4], bf[4];
#pragma unroll
      for (int mi = 0; mi < 4; ++mi)
        af[mi] = *(const short8*)&As[(wm * 64 + mi * 16 + l15) * 64 + slot * 8];
#pragma unroll
      for (int ni = 0; ni < 4; ++ni)
        bf[ni] = *(const short8*)&Bs[(wn * 64 + ni * 16 + l15) * 64 + slot * 8];
#pragma unroll
      for (int mi = 0; mi < 4; ++mi)
#pragma unroll
        for (int ni = 0; ni < 4; ++ni)
          acc[mi][ni] = __builtin_amdgcn_mfma_f32_16x16x32_bf16(af[mi], bf[ni], acc[mi][ni], 0, 0, 0);
    }
    __syncthreads();
  }

  // ---- epilogue ----
  const int srow0 = bm * 128 + wm * 64;
  if (bn < 20) {
    __hip_bfloat16* dst; int ld;
    if (bn < 16) { dst = Qb + (size_t)bn * 128;        ld = 2048; }
    else         { dst = Kb + (size_t)(bn - 16) * 128; ld = 512;  }
#pragma unroll
    for (int mi = 0; mi < 4; ++mi)
#pragma unroll
      for (int ni = 0; ni < 4; ++ni) {
        int dcol = wn * 64 + ni * 16 + l15;
        int srow = srow0 + mi * 16 + lg * 4;
#pragma unroll
        for (int r = 0; r < 4; ++r)
          dst[(size_t)(srow + r) * ld + dcol] = __float2bfloat16(acc[mi][ni][r]);
      }
  } else {
    const int c0 = (bn - 20) * 128;
#pragma unroll
    for (int mi = 0; mi < 4; ++mi)
#pragma unroll
      for (int ni = 0; ni < 4; ++ni) {
        int c  = c0 + wn * 64 + ni * 16 + l15;
        int s0 = srow0 + mi * 16 + lg * 4;
        s16x4 o;
#pragma unroll
        for (int r = 0; r < 4; ++r) o[r] = f2bf_s(acc[mi][ni][r]);
        *(s16x4*)&Vt[(size_t)c * 4096 + s0] = o;   // transposed write, 8B/lane
      }
  }
}

// ---------------- GEMM2: C[M][N] f32 = A[M][K] bf16 . Bt[N][K]^T bf16 ----------------
__global__ __launch_bounds__(256) void gemm_bt(
    const __hip_bfloat16* __restrict__ A, const __hip_bfloat16* __restrict__ Bt,
    float* __restrict__ C, int M, int N, int K) {
  const int tid = threadIdx.x;
  const int wave = tid >> 6, lane = tid & 63;
  const int l15 = lane & 15, lg = lane >> 4;
  const int bm = blockIdx.x, bn = blockIdx.y;
  const int wm = wave >> 1, wn = wave & 1;

  __shared__ __hip_bfloat16 As[128 * 64];
  __shared__ __hip_bfloat16 Bs[128 * 64];

  f32x4 acc[4][4] = {};
  const int lrow = lane >> 3;
  const int lslot = lane & 7;
  const int scol = (lslot ^ lrow) * 8;
  const size_t abase = (size_t)bm * 128 * K;
  const size_t bbase = (size_t)bn * 128 * K;
  const int r3 = l15 & 7;

  for (int k0 = 0; k0 < K; k0 += 64) {
#pragma unroll
    for (int i = 0; i < 4; ++i) {
      int seg = i * 4 + wave;
      int row = seg * 8 + lrow;
      gload16(A + abase + (size_t)row * K + k0 + scol, &As[seg * 512]);
      gload16(Bt + bbase + (size_t)row * K + k0 + scol, &Bs[seg * 512]);
    }
    __syncthreads();
#pragma unroll
    for (int ks = 0; ks < 2; ++ks) {
      const int slot = (ks * 4 + lg) ^ r3;
      short8 af[4], bf[4];
#pragma unroll
      for (int mi = 0; mi < 4; ++mi)
        af[mi] = *(const short8*)&As[(wm * 64 + mi * 16 + l15) * 64 + slot * 8];
#pragma unroll
      for (int ni = 0; ni < 4; ++ni)
        bf[ni] = *(const short8*)&Bs[(wn * 64 + ni * 16 + l15) * 64 + slot * 8];
#pragma unroll
      for (int mi = 0; mi < 4; ++mi)
#pragma unroll
        for (int ni = 0; ni < 4; ++ni)
          acc[mi][ni] = __builtin_amdgcn_mfma_f32_16x16x32_bf16(af[mi], bf[ni], acc[mi][ni], 0, 0, 0);
    }
    __syncthreads();
  }
#pragma unroll
  for (int mi = 0; mi < 4; ++mi)
#pragma unroll
    for (int ni = 0; ni < 4; ++ni) {
      int row = bm * 128 + wm * 64 + mi * 16 + lg * 4;
      int col = bn * 128 + wn * 64 + ni * 16 + l15;
#pragma unroll
      for (int r = 0; r < 4; ++r)
        C[(size_t)(row + r) * N + col] = acc[mi][ni][r];
    }
}

// ---------------- block-sparse attention ----------------
// LDS-staged K/V via global_load_lds (16B), double-buffered, counted vmcnt + raw barriers.
// K tile [64][128] and V tile [128][64], XOR-swizzled (pre-swizzled source + swizzled read).
// grid = nb*NH = 1024 blocks; 4 waves; wave w owns q-rows [w*16, w*16+16).
__device__ __forceinline__ void stageK(const __hip_bfloat16* __restrict__ Kb, int kb, int kvh,
                                       __hip_bfloat16* buf, int wave, int lane) {
#pragma unroll
  for (int i = 0; i < 4; ++i) {
    int chunk = i * 4 + wave;            // 0..15, each 1KB
    int row = chunk * 4 + (lane >> 4);   // 0..63
    int slot = lane & 15;                // 16B slot in 256B row
    gload16(Kb + (size_t)(kb * 64 + row) * 512 + kvh * 128 + ((slot ^ (row & 15)) * 8),
            buf + chunk * 512);
  }
}

__device__ __forceinline__ void stageV(const __hip_bfloat16* __restrict__ Vt, int kb, int kvh,
                                       __hip_bfloat16* buf, int wave, int lane) {
#pragma unroll
  for (int i = 0; i < 4; ++i) {
    int chunk = i * 4 + wave;            // 0..15, each 1KB
    int row = chunk * 8 + (lane >> 3);   // 0..127
    int slot = lane & 7;                 // 16B slot in 128B row
    gload16(Vt + (size_t)(kvh * 128 + row) * 4096 + kb * 64 + ((slot ^ (row & 7)) * 8),
            buf + chunk * 512);
  }
}

#define ACQ(N) do { \
  asm volatile("s_waitcnt vmcnt(" #N ")" ::: "memory"); \
  __builtin_amdgcn_s_barrier(); \
  __builtin_amdgcn_sched_barrier(0); \
} while (0)

#define REL() do { \
  __builtin_amdgcn_sched_barrier(0); \
  __builtin_amdgcn_s_barrier(); \
} while (0)

__global__ __launch_bounds__(256) void attn_kernel(
    const __hip_bfloat16* __restrict__ Qb,  // [4096][2048]
    const __hip_bfloat16* __restrict__ Kb,  // [4096][512]
    const __hip_bfloat16* __restrict__ Vt,  // [512][4096]  (channel-major)
    const float* __restrict__ amask,        // [4096]
    __hip_bfloat16* __restrict__ AO)        // [4096][2048]
{
  const int bid = blockIdx.x;
  const int h = bid & 15;
  const int bi = bid >> 4;
  const int kvh = h >> 2;
  const int tid = threadIdx.x;
  const int wave = tid >> 6, lane = tid & 63;
  const int l15 = lane & 15, lg = lane >> 4;

  // static block selection (matches _select_key_blocks): <=6 blocks, block-uniform
  int sel[6]; int nsel = 0;
  {
    int gtop = bi >> 2;
    for (int j = 0; j <= bi; ++j) {
      bool pick = (j == 0) || (j >= bi - 3) || (((j & 3) == 0) && ((j >> 2) >= gtop - 1));
      if (pick && nsel < 6) sel[nsel++] = j;
    }
  }

  __shared__ __hip_bfloat16 kv[2][8192];   // K: [64][128], V: [128][64]; 2 x 16KB
  __shared__ __hip_bfloat16 Pb[64 * 72];   // P tile, wave-private rows

  // Q fragments in registers (A operand, 4 k-steps of 32)
  short8 qf[4];
  {
    const __hip_bfloat16* qbase =
        Qb + (size_t)(bi * 64 + wave * 16 + l15) * 2048 + h * 128 + lg * 8;
#pragma unroll
    for (int ks = 0; ks < 4; ++ks) qf[ks] = *(const short8*)(qbase + ks * 32);
  }

  // ---- phase 1: QK^T, K double-buffered ----
  f32x4 sc[6][4] = {};
  stageK(Kb, sel[0], kvh, kv[0], wave, lane);
#pragma unroll
  for (int j = 0; j < 6; ++j) {
    if (j < nsel) {
      if (j + 1 < nsel) {
        stageK(Kb, sel[j + 1], kvh, kv[(j + 1) & 1], wave, lane);
        ACQ(4);
      } else {
        ACQ(0);
      }
      const __hip_bfloat16* kbuf = kv[j & 1];
#pragma unroll
      for (int nf = 0; nf < 4; ++nf) {
        int row = nf * 16 + l15;
#pragma unroll
        for (int ks = 0; ks < 4; ++ks) {
          int slot = (ks * 4 + lg) ^ l15;
          short8 bfr = *(const short8*)&kbuf[row * 128 + slot * 8];
          sc[j][nf] = __builtin_amdgcn_mfma_f32_16x16x32_bf16(qf[ks], bfr, sc[j][nf], 0, 0, 0);
        }
      }
      REL();
    }
  }

  // ---- issue V0 stage early; it flies during the softmax VALU pass ----
  stageV(Vt, sel[0], kvh, kv[0], wave, lane);

  // ---- phase 2: mask + softmax (register-only; rows live in (lg, r)) ----
  float rowmax[4] = {-3.0e38f, -3.0e38f, -3.0e38f, -3.0e38f};
#pragma unroll
  for (int j = 0; j < 6; ++j) {
    if (j >= nsel) continue;
    int kb = sel[j];
#pragma unroll
    for (int nf = 0; nf < 4; ++nf) {
      int keyg = kb * 64 + nf * 16 + l15;
      float mterm = (1.0f - amask[keyg]) * NEGV;
      int keyl = nf * 16 + l15;
#pragma unroll
      for (int r = 0; r < 4; ++r) {
        float s = sc[j][nf][r] * SCALE + mterm;
        if (kb == bi) {
          int qrow = wave * 16 + lg * 4 + r;
          if (keyl > qrow) s = NEGV;
        }
        sc[j][nf][r] = s;
        rowmax[r] = fmaxf(rowmax[r], s);
      }
    }
  }
#pragma unroll
  for (int r = 0; r < 4; ++r) {
    float v = rowmax[r];
    v = fmaxf(v, __shfl_xor(v, 1)); v = fmaxf(v, __shfl_xor(v, 2));
    v = fmaxf(v, __shfl_xor(v, 4)); v = fmaxf(v, __shfl_xor(v, 8));
    rowmax[r] = v;
  }
  float rinv[4] = {0.f, 0.f, 0.f, 0.f};
#pragma unroll
  for (int j = 0; j < 6; ++j) {
    if (j >= nsel) continue;
#pragma unroll
    for (int nf = 0; nf < 4; ++nf)
#pragma unroll
      for (int r = 0; r < 4; ++r) {
        float p = __expf(sc[j][nf][r] - rowmax[r]);
        sc[j][nf][r] = p;
        rinv[r] += p;
      }
  }
#pragma unroll
  for (int r = 0; r < 4; ++r) {
    float v = rinv[r];
    v += __shfl_xor(v, 1); v += __shfl_xor(v, 2);
    v += __shfl_xor(v, 4); v += __shfl_xor(v, 8);
    rinv[r] = 1.0f / v;
  }

  // ---- phase 3: PV, V double-buffered ----
  f32x4 oacc[8] = {};
#pragma unroll
  for (int j = 0; j < 6; ++j) {
    if (j < nsel) {
      if (j + 1 < nsel)
        stageV(Vt, sel[j + 1], kvh, kv[(j + 1) & 1], wave, lane);
      // write normalized P tile for this j (wave-private rows; same-wave read-back)
#pragma unroll
      for (int nf = 0; nf < 4; ++nf)
#pragma unroll
        for (int r = 0; r < 4; ++r) {
          int qrow = wave * 16 + lg * 4 + r;
          Pb[qrow * 72 + nf * 16 + l15] = __float2bfloat16(sc[j][nf][r] * rinv[r]);
        }
      if (j + 1 < nsel) { ACQ(4); } else { ACQ(0); }
      const __hip_bfloat16* vbuf = kv[j & 1];
#pragma unroll
      for (int ks = 0; ks < 2; ++ks) {
        short8 pa = *(const short8*)&Pb[(wave * 16 + l15) * 72 + ks * 32 + lg * 8];
#pragma unroll
        for (int df = 0; df < 8; ++df) {
          int row = df * 16 + l15;
          int slot = (ks * 4 + lg) ^ (l15 & 7);
          short8 vb = *(const short8*)&vbuf[row * 64 + slot * 8];
          oacc[df] = __builtin_amdgcn_mfma_f32_16x16x32_bf16(pa, vb, oacc[df], 0, 0, 0);
        }
      }
      REL();
    }
  }

  // ---- phase 4: write AO ----
#pragma unroll
  for (int df = 0; df < 8; ++df)
#pragma unroll
    for (int r = 0; r < 4; ++r) {
      int qrow = bi * 64 + wave * 16 + lg * 4 + r;
      AO[(size_t)qrow * 2048 + h * 128 + df * 16 + l15] = __float2bfloat16(oacc[df][r]);
    }
}

// ---------------- launch ----------------
extern "C" void kernel_launch(void* const* d_in, const int* in_sizes, int n_in,
                              void* d_out, int out_size, void* d_ws, size_t ws_size,
                              hipStream_t stream) {
  const float* hidden = (const float*)d_in[0];
  const float* cosb   = (const float*)d_in[1];
  const float* sinb   = (const float*)d_in[2];
  const float* Wq     = (const float*)d_in[3];
  const float* Wk     = (const float*)d_in[4];
  const float* Wv     = (const float*)d_in[5];
  const float* Wo     = (const float*)d_in[6];
  const float* amask  = (const float*)d_in[7];

  char* ws = (char*)d_ws;
  __hip_bfloat16* Xb   = (__hip_bfloat16*)(ws);               // 16,777,216 B  [4096][2048]
  __hip_bfloat16* Wt   = (__hip_bfloat16*)(ws + 16777216);    // 12,582,912 B  [3072][2048]
  __hip_bfloat16* Wot  = (__hip_bfloat16*)(ws + 29360128);    //  8,388,608 B  [2048][2048]
  __hip_bfloat16* Qb   = (__hip_bfloat16*)(ws + 37748736);    // 16,777,216 B  [4096][2048]
  __hip_bfloat16* Kb   = (__hip_bfloat16*)(ws + 54525952);    //  4,194,304 B  [4096][512]
  __hip_bfloat16* Vt   = (__hip_bfloat16*)(ws + 58720256);    //  4,194,304 B  [512][4096]
  __hip_bfloat16* AO   = Xb;  // Xb dead after gemm_qkv; reuse for attention output

  conv_hidden<<<8192, 256, 0, stream>>>(hidden, Xb);
  transpose_f32_to_bf16<<<dim3(32, 32), 256, 0, stream>>>(Wq, Wt, 2048, 2048);
  transpose_f32_to_bf16<<<dim3(32, 8),  256, 0, stream>>>(Wk, Wt + (size_t)2048 * 2048, 2048, 512);
  transpose_f32_to_bf16<<<dim3(32, 8),  256, 0, stream>>>(Wv, Wt + (size_t)2560 * 2048, 2048, 512);
  transpose_f32_to_bf16<<<dim3(32, 32), 256, 0, stream>>>(Wo, Wot, 2048, 2048);

  gemm_qkv<<<dim3(32, 24), 256, 0, stream>>>(Xb, Wt, Qb, Kb, Vt);

  rope_inplace<<<1280, 256, 0, stream>>>(cosb, sinb, Qb, Kb);

  attn_kernel<<<1024, 256, 0, stream>>>(Qb, Kb, Vt, amask, AO);

  gemm_bt<<<dim3(32, 16), 256, 0, stream>>>(AO, Wot, (float*)d_out, 4096, 2048, 2048);
}

// Round 7
// 174.757 us; speedup vs baseline: 1.4415x; 1.2922x over previous
//
#include <hip/hip_runtime.h>
#include <hip/hip_bf16.h>

// HumanVAttention: QKV proj -> in-place RoPE -> V transpose -> GQA block-sparse attn -> out proj
// B=1 S=4096 HID=2048 NH=16 NKV=4 HD=128 BLK=64 LOCAL=4 GNB=2 STRIDE=4 ROT=64

typedef short short8 __attribute__((ext_vector_type(8)));
typedef float f32x4  __attribute__((ext_vector_type(4)));

#define NEGV   (-1.0e9f)
#define SCALE  (0.08838834764831845f)

__device__ __forceinline__ void gload16(const void* g, void* l) {
  __builtin_amdgcn_global_load_lds(
      (const __attribute__((address_space(1))) unsigned int*)g,
      (__attribute__((address_space(3))) unsigned int*)l, 16, 0, 0);
}

__device__ __forceinline__ float bf2f(short s) {
  union { unsigned u; float f; } c;
  c.u = ((unsigned)(unsigned short)s) << 16;
  return c.f;
}

__device__ __forceinline__ short f2bf_s(float f) {
  __hip_bfloat16 b = __float2bfloat16(f);
  short s;
  __builtin_memcpy(&s, &b, 2);
  return s;
}

// ---------------- elementwise convert hidden f32 -> bf16 ----------------
__global__ void conv_hidden(const float* __restrict__ H, __hip_bfloat16* __restrict__ X) {
  size_t t = (size_t)blockIdx.x * 256 + threadIdx.x;   // one float4 per thread
  float4 v = *(const float4*)(H + t * 4);
  __hip_bfloat16* o = X + t * 4;
  o[0] = __float2bfloat16(v.x); o[1] = __float2bfloat16(v.y);
  o[2] = __float2bfloat16(v.z); o[3] = __float2bfloat16(v.w);
}

// ---------------- tiled transpose f32[R][C] -> bf16 dst[C][R] ----------------
__global__ void transpose_f32_to_bf16(const float* __restrict__ src,
                                      __hip_bfloat16* __restrict__ dst,
                                      int R, int C) {
  __shared__ __hip_bfloat16 tile[64][73];
  int r0 = blockIdx.x * 64, c0 = blockIdx.y * 64;
  int c = threadIdx.x & 63, rq = threadIdx.x >> 6;
#pragma unroll
  for (int i = 0; i < 16; ++i) {
    int r = i * 4 + rq;
    tile[r][c] = __float2bfloat16(src[(size_t)(r0 + r) * C + c0 + c]);
  }
  __syncthreads();
#pragma unroll
  for (int i = 0; i < 16; ++i) {
    int cc = i * 4 + rq;
    dst[(size_t)(c0 + cc) * R + r0 + c] = tile[c][cc];
  }
}

// ---------------- V transpose: Vb[s][c] (bf16, [4096][512]) -> Vt[c][s] ----------------
__global__ void transpose_v(const __hip_bfloat16* __restrict__ Vb,
                            __hip_bfloat16* __restrict__ Vt) {
  __shared__ __hip_bfloat16 tile[64][73];
  int s0 = blockIdx.x * 64, c0 = blockIdx.y * 64;
  int c = threadIdx.x & 63, rq = threadIdx.x >> 6;
#pragma unroll
  for (int i = 0; i < 16; ++i) {
    int r = i * 4 + rq;
    tile[r][c] = Vb[(size_t)(s0 + r) * 512 + c0 + c];
  }
  __syncthreads();
#pragma unroll
  for (int i = 0; i < 16; ++i) {
    int cc = i * 4 + rq;
    Vt[(size_t)(c0 + cc) * 4096 + s0 + c] = tile[c][cc];
  }
}

// ---------------- in-place partial RoPE on Qb and Kb (verified R6) ----------------
__global__ void rope_inplace(const float* __restrict__ cosb, const float* __restrict__ sinb,
                             __hip_bfloat16* __restrict__ Qb, __hip_bfloat16* __restrict__ Kb) {
  int t = blockIdx.x * 256 + threadIdx.x;
  __hip_bfloat16* p;
  int s;
  if (t < 262144) {               // Q: s = t>>6, then 16 h x 4 g
    s = t >> 6;
    int rem = t & 63;
    p = Qb + (size_t)s * 2048 + (rem >> 2) * 128 + (rem & 3) * 8;
  } else {                        // K: s = tk>>4, then 4 h x 4 g
    int tk = t - 262144;
    s = tk >> 4;
    int rem = tk & 15;
    p = Kb + (size_t)s * 512 + (rem >> 2) * 128 + (rem & 3) * 8;
  }
  const int g8 = (t & 3) * 8;     // d offset in [0,32)
  const float* cp = cosb + (size_t)s * 64 + g8;
  const float* sp = sinb + (size_t)s * 64 + g8;
  short8 a = *(const short8*)p;          // x[d],    d in [0,32)
  short8 b = *(const short8*)(p + 32);   // x[d+32]
  float ca[8], sa[8], cb[8], sb[8];
  *(float4*)&ca[0] = *(const float4*)cp;        *(float4*)&ca[4] = *(const float4*)(cp + 4);
  *(float4*)&cb[0] = *(const float4*)(cp + 32); *(float4*)&cb[4] = *(const float4*)(cp + 36);
  *(float4*)&sa[0] = *(const float4*)sp;        *(float4*)&sa[4] = *(const float4*)(sp + 4);
  *(float4*)&sb[0] = *(const float4*)(sp + 32); *(float4*)&sb[4] = *(const float4*)(sp + 36);
  short8 oa, ob;
#pragma unroll
  for (int i = 0; i < 8; ++i) {
    float av = bf2f(a[i]), bv = bf2f(b[i]);
    oa[i] = f2bf_s(av * ca[i] - bv * sa[i]);   // rot_half: d<32 -> -x[d+32]
    ob[i] = f2bf_s(bv * cb[i] + av * sb[i]);   // d>=32   -> +x[d-32]
  }
  *(short8*)p = oa;
  *(short8*)(p + 32) = ob;
}

// ---------------- GEMM1: 256x256 tile, BK=64, 8 waves, double-buffered LDS ----------------
// X[4096][2048] . Wt[3072][2048]^T -> Qb/Kb/Vb (row-major, coalesced).
// Pipeline: at iteration top, vmcnt(0)+barrier (only tile-(t+1) loads outstanding, issued a
// full tile ago -> cheap wait); then issue tile-(t+2)... i.e. next tile's 8 global_load_lds
// into the other buffer; then 64 MFMA/wave. Loads stay in flight across the whole compute.
// Swizzle: pre-swizzled global source col + swizzled ds_read (row&7 involution, rule #21).
__global__ __launch_bounds__(512) void gemm_qkv256(
    const __hip_bfloat16* __restrict__ A, const __hip_bfloat16* __restrict__ Bt,
    __hip_bfloat16* __restrict__ Qb, __hip_bfloat16* __restrict__ Kb,
    __hip_bfloat16* __restrict__ Vb) {
  const int K = 2048;
  const int tid = threadIdx.x;
  const int wave = tid >> 6, lane = tid & 63;
  const int l15 = lane & 15, lg = lane >> 4;
  const int bm = blockIdx.x, bn = blockIdx.y;
  const int wm = wave >> 2, wn = wave & 3;        // 2 x 4 wave grid; per-wave C: 128x64

  __shared__ __hip_bfloat16 lds[2][32768];        // [buf][ A: 0..16383 | B: 16384..32767 ]

  f32x4 acc[8][4] = {};
  const int lrow = lane >> 3;                     // 0..7 row within 8-row segment
  const int lslot = lane & 7;                     // 16B slot within 128B row
  const size_t abase = (size_t)bm * 256 * K;
  const size_t bbase = (size_t)bn * 256 * K;
  const int r3 = l15 & 7;

  // stage one K-tile (A 256x64 + B 256x64) into buf: 8 global_load_lds per thread
#define STAGE_TILE(buf, k0)                                                        \
  do {                                                                             \
    _Pragma("unroll")                                                              \
    for (int c = 0; c < 4; ++c) {                                                  \
      int seg = c * 8 + wave;                                                      \
      int row = seg * 8 + lrow;                                                    \
      int col = (lslot ^ (row & 7)) * 8;                                           \
      gload16(A + abase + (size_t)row * K + (k0) + col, &lds[buf][seg * 512]);     \
      gload16(Bt + bbase + (size_t)row * K + (k0) + col, &lds[buf][16384 + seg * 512]); \
    }                                                                              \
  } while (0)

  STAGE_TILE(0, 0);

  for (int t = 0; t < 32; ++t) {
    asm volatile("s_waitcnt vmcnt(0)" ::: "memory");
    __builtin_amdgcn_s_barrier();
    __builtin_amdgcn_sched_barrier(0);
    if (t + 1 < 32) {
      const int nb = (t + 1) & 1;
      if (nb) STAGE_TILE(1, (t + 1) * 64); else STAGE_TILE(0, (t + 1) * 64);
    }
    const __hip_bfloat16* As_ = lds[t & 1];
    const __hip_bfloat16* Bs_ = lds[t & 1] + 16384;
#pragma unroll
    for (int kk = 0; kk < 2; ++kk) {
      const int slot = (kk * 4 + lg) ^ r3;
      short8 bf[4];
#pragma unroll
      for (int ni = 0; ni < 4; ++ni)
        bf[ni] = *(const short8*)&Bs_[(wn * 64 + ni * 16 + l15) * 64 + slot * 8];
#pragma unroll
      for (int mh = 0; mh < 2; ++mh) {
        short8 af[4];
#pragma unroll
        for (int mi = 0; mi < 4; ++mi)
          af[mi] = *(const short8*)&As_[(wm * 128 + mh * 64 + mi * 16 + l15) * 64 + slot * 8];
        __builtin_amdgcn_s_setprio(1);
#pragma unroll
        for (int mi = 0; mi < 4; ++mi)
#pragma unroll
          for (int ni = 0; ni < 4; ++ni)
            acc[mh * 4 + mi][ni] =
                __builtin_amdgcn_mfma_f32_16x16x32_bf16(af[mi], bf[ni], acc[mh * 4 + mi][ni], 0, 0, 0);
        __builtin_amdgcn_s_setprio(0);
      }
    }
  }
#undef STAGE_TILE

  // ---- epilogue: bn tile (256 cols) maps wholly to Q (bn<8), K (8,9) or V (10,11) ----
  __hip_bfloat16* dst; int ldc, coff;
  if (bn < 8)       { dst = Qb; ldc = 2048; coff = bn * 256; }
  else if (bn < 10) { dst = Kb; ldc = 512;  coff = bn * 256 - 2048; }
  else              { dst = Vb; ldc = 512;  coff = bn * 256 - 2560; }
#pragma unroll
  for (int m8 = 0; m8 < 8; ++m8)
#pragma unroll
    for (int ni = 0; ni < 4; ++ni) {
      int row = bm * 256 + wm * 128 + m8 * 16 + lg * 4;
      int col = coff + wn * 64 + ni * 16 + l15;
#pragma unroll
      for (int r = 0; r < 4; ++r)
        dst[(size_t)(row + r) * ldc + col] = __float2bfloat16(acc[m8][ni][r]);
    }
}

// ---------------- GEMM2: C[M][N] f32 = A[M][K] bf16 . Bt[N][K]^T bf16 (verified 128^2) ----------------
__global__ __launch_bounds__(256) void gemm_bt(
    const __hip_bfloat16* __restrict__ A, const __hip_bfloat16* __restrict__ Bt,
    float* __restrict__ C, int M, int N, int K) {
  const int tid = threadIdx.x;
  const int wave = tid >> 6, lane = tid & 63;
  const int l15 = lane & 15, lg = lane >> 4;
  const int bm = blockIdx.x, bn = blockIdx.y;
  const int wm = wave >> 1, wn = wave & 1;

  __shared__ __hip_bfloat16 As[128 * 64];
  __shared__ __hip_bfloat16 Bs[128 * 64];

  f32x4 acc[4][4] = {};
  const int lrow = lane >> 3;
  const int lslot = lane & 7;
  const int scol = (lslot ^ lrow) * 8;
  const size_t abase = (size_t)bm * 128 * K;
  const size_t bbase = (size_t)bn * 128 * K;
  const int r3 = l15 & 7;

  for (int k0 = 0; k0 < K; k0 += 64) {
#pragma unroll
    for (int i = 0; i < 4; ++i) {
      int seg = i * 4 + wave;
      int row = seg * 8 + lrow;
      gload16(A + abase + (size_t)row * K + k0 + scol, &As[seg * 512]);
      gload16(Bt + bbase + (size_t)row * K + k0 + scol, &Bs[seg * 512]);
    }
    __syncthreads();
#pragma unroll
    for (int ks = 0; ks < 2; ++ks) {
      const int slot = (ks * 4 + lg) ^ r3;
      short8 af[4], bf[4];
#pragma unroll
      for (int mi = 0; mi < 4; ++mi)
        af[mi] = *(const short8*)&As[(wm * 64 + mi * 16 + l15) * 64 + slot * 8];
#pragma unroll
      for (int ni = 0; ni < 4; ++ni)
        bf[ni] = *(const short8*)&Bs[(wn * 64 + ni * 16 + l15) * 64 + slot * 8];
#pragma unroll
      for (int mi = 0; mi < 4; ++mi)
#pragma unroll
        for (int ni = 0; ni < 4; ++ni)
          acc[mi][ni] = __builtin_amdgcn_mfma_f32_16x16x32_bf16(af[mi], bf[ni], acc[mi][ni], 0, 0, 0);
    }
    __syncthreads();
  }
#pragma unroll
  for (int mi = 0; mi < 4; ++mi)
#pragma unroll
    for (int ni = 0; ni < 4; ++ni) {
      int row = bm * 128 + wm * 64 + mi * 16 + lg * 4;
      int col = bn * 128 + wn * 64 + ni * 16 + l15;
#pragma unroll
      for (int r = 0; r < 4; ++r)
        C[(size_t)(row + r) * N + col] = acc[mi][ni][r];
    }
}

// ---------------- block-sparse attention (R3-verified staged version) ----------------
// grid = nb*NH = 1024 blocks; block = 256 threads = 4 waves; wave w owns q-rows [w*16, w*16+16)
__global__ __launch_bounds__(256, 2) void attn_kernel(
    const __hip_bfloat16* __restrict__ Qb,  // [4096][2048]
    const __hip_bfloat16* __restrict__ Kb,  // [4096][512]
    const __hip_bfloat16* __restrict__ Vt,  // [512][4096]  (channel-major)
    const float* __restrict__ amask,        // [4096]
    __hip_bfloat16* __restrict__ AO)        // [4096][2048]
{
  const int bid = blockIdx.x;
  const int h = bid & 15;
  const int bi = bid >> 4;
  const int kvh = h >> 2;
  const int tid = threadIdx.x;
  const int wave = tid >> 6, lane = tid & 63;
  const int l15 = lane & 15, lg = lane >> 4;

  // static block selection (matches _select_key_blocks): <=6 blocks
  int sel[6]; int nsel = 0;
  {
    int gtop = bi >> 2;
    for (int j = 0; j <= bi; ++j) {
      bool pick = (j == 0) || (j >= bi - 3) || (((j & 3) == 0) && ((j >> 2) >= gtop - 1));
      if (pick && nsel < 6) sel[nsel++] = j;
    }
  }

  __shared__ __hip_bfloat16 kvs[128 * 72];   // K phase: [64][136]; V phase: [128][72]
  __shared__ __hip_bfloat16 Pb[64 * 72];     // P tile [64 q][64 k + pad]

  // Q fragments in registers (A operand, 4 k-steps of 32)
  short8 qf[4];
  {
    const __hip_bfloat16* qbase =
        Qb + (size_t)(bi * 64 + wave * 16 + l15) * 2048 + h * 128 + lg * 8;
#pragma unroll
    for (int ks = 0; ks < 4; ++ks) qf[ks] = *(const short8*)(qbase + ks * 32);
  }

  // ---- phase 1: scores for all selected blocks (held in registers) ----
  f32x4 sc[6][4] = {};
#pragma unroll
  for (int j = 0; j < 6; ++j) {
    if (j < nsel) {
      int kb = sel[j];
#pragma unroll
      for (int i = 0; i < 4; ++i) {
        int e = (i * 256 + tid) * 8;        // 64*128 elements
        int r = e >> 7, c = e & 127;
        short8 v = *(const short8*)(Kb + (size_t)(kb * 64 + r) * 512 + kvh * 128 + c);
        *(short8*)&kvs[r * 136 + c] = v;
      }
      __syncthreads();
#pragma unroll
      for (int nf = 0; nf < 4; ++nf)
#pragma unroll
        for (int ks = 0; ks < 4; ++ks) {
          short8 bfr = *(const short8*)&kvs[(nf * 16 + l15) * 136 + ks * 32 + lg * 8];
          sc[j][nf] = __builtin_amdgcn_mfma_f32_16x16x32_bf16(qf[ks], bfr, sc[j][nf], 0, 0, 0);
        }
      __syncthreads();
    }
  }

  // ---- phase 2: mask + softmax (rows live in (lg, r)) ----
  float rowmax[4] = {-3.0e38f, -3.0e38f, -3.0e38f, -3.0e38f};
#pragma unroll
  for (int j = 0; j < 6; ++j) {
    if (j >= nsel) continue;
    int kb = sel[j];
#pragma unroll
    for (int nf = 0; nf < 4; ++nf) {
      int keyg = kb * 64 + nf * 16 + l15;
      float mterm = (1.0f - amask[keyg]) * NEGV;
      int keyl = nf * 16 + l15;
#pragma unroll
      for (int r = 0; r < 4; ++r) {
        float s = sc[j][nf][r] * SCALE + mterm;
        if (kb == bi) {
          int qrow = wave * 16 + lg * 4 + r;
          if (keyl > qrow) s = NEGV;
        }
        sc[j][nf][r] = s;
        rowmax[r] = fmaxf(rowmax[r], s);
      }
    }
  }
#pragma unroll
  for (int r = 0; r < 4; ++r) {
    float v = rowmax[r];
    v = fmaxf(v, __shfl_xor(v, 1)); v = fmaxf(v, __shfl_xor(v, 2));
    v = fmaxf(v, __shfl_xor(v, 4)); v = fmaxf(v, __shfl_xor(v, 8));
    rowmax[r] = v;
  }
  float rinv[4] = {0.f, 0.f, 0.f, 0.f};
#pragma unroll
  for (int j = 0; j < 6; ++j) {
    if (j >= nsel) continue;
#pragma unroll
    for (int nf = 0; nf < 4; ++nf)
#pragma unroll
      for (int r = 0; r < 4; ++r) {
        float p = __expf(sc[j][nf][r] - rowmax[r]);
        sc[j][nf][r] = p;
        rinv[r] += p;
      }
  }
#pragma unroll
  for (int r = 0; r < 4; ++r) {
    float v = rinv[r];
    v += __shfl_xor(v, 1); v += __shfl_xor(v, 2);
    v += __shfl_xor(v, 4); v += __shfl_xor(v, 8);
    rinv[r] = 1.0f / v;
  }

  // ---- phase 3: PV ----
  f32x4 oacc[8] = {};
#pragma unroll
  for (int j = 0; j < 6; ++j) {
    if (j < nsel) {
      int kb = sel[j];
#pragma unroll
      for (int nf = 0; nf < 4; ++nf)
#pragma unroll
        for (int r = 0; r < 4; ++r) {
          int qrow = wave * 16 + lg * 4 + r;
          Pb[qrow * 72 + nf * 16 + l15] = __float2bfloat16(sc[j][nf][r] * rinv[r]);
        }
#pragma unroll
      for (int i = 0; i < 4; ++i) {
        int e = (i * 256 + tid) * 8;        // 128*64 elements
        int d = e >> 6, c = e & 63;
        short8 v = *(const short8*)(Vt + (size_t)(kvh * 128 + d) * 4096 + kb * 64 + c);
        *(short8*)&kvs[d * 72 + c] = v;
      }
      __syncthreads();
#pragma unroll
      for (int ks = 0; ks < 2; ++ks) {
        short8 pa = *(const short8*)&Pb[(wave * 16 + l15) * 72 + ks * 32 + lg * 8];
#pragma unroll
        for (int df = 0; df < 8; ++df) {
          short8 vb = *(const short8*)&kvs[(df * 16 + l15) * 72 + ks * 32 + lg * 8];
          oacc[df] = __builtin_amdgcn_mfma_f32_16x16x32_bf16(pa, vb, oacc[df], 0, 0, 0);
        }
      }
      __syncthreads();
    }
  }

  // ---- phase 4: write AO ----
#pragma unroll
  for (int df = 0; df < 8; ++df)
#pragma unroll
    for (int r = 0; r < 4; ++r) {
      int qrow = bi * 64 + wave * 16 + lg * 4 + r;
      AO[(size_t)qrow * 2048 + h * 128 + df * 16 + l15] = __float2bfloat16(oacc[df][r]);
    }
}

// ---------------- launch ----------------
extern "C" void kernel_launch(void* const* d_in, const int* in_sizes, int n_in,
                              void* d_out, int out_size, void* d_ws, size_t ws_size,
                              hipStream_t stream) {
  const float* hidden = (const float*)d_in[0];
  const float* cosb   = (const float*)d_in[1];
  const float* sinb   = (const float*)d_in[2];
  const float* Wq     = (const float*)d_in[3];
  const float* Wk     = (const float*)d_in[4];
  const float* Wv     = (const float*)d_in[5];
  const float* Wo     = (const float*)d_in[6];
  const float* amask  = (const float*)d_in[7];

  char* ws = (char*)d_ws;
  __hip_bfloat16* Xb   = (__hip_bfloat16*)(ws);               // 16,777,216 B  [4096][2048]
  __hip_bfloat16* Wt   = (__hip_bfloat16*)(ws + 16777216);    // 12,582,912 B  [3072][2048]
  __hip_bfloat16* Wot  = (__hip_bfloat16*)(ws + 29360128);    //  8,388,608 B  [2048][2048]
  __hip_bfloat16* Qb   = (__hip_bfloat16*)(ws + 37748736);    // 16,777,216 B  [4096][2048]
  __hip_bfloat16* Kb   = (__hip_bfloat16*)(ws + 54525952);    //  4,194,304 B  [4096][512]
  __hip_bfloat16* Vb   = (__hip_bfloat16*)(ws + 58720256);    //  4,194,304 B  [4096][512]
  __hip_bfloat16* Vt   = (__hip_bfloat16*)(ws + 62914560);    //  4,194,304 B  [512][4096]
  __hip_bfloat16* AO   = Xb;  // Xb dead after gemm_qkv256; reuse for attention output

  conv_hidden<<<8192, 256, 0, stream>>>(hidden, Xb);
  transpose_f32_to_bf16<<<dim3(32, 32), 256, 0, stream>>>(Wq, Wt, 2048, 2048);
  transpose_f32_to_bf16<<<dim3(32, 8),  256, 0, stream>>>(Wk, Wt + (size_t)2048 * 2048, 2048, 512);
  transpose_f32_to_bf16<<<dim3(32, 8),  256, 0, stream>>>(Wv, Wt + (size_t)2560 * 2048, 2048, 512);
  transpose_f32_to_bf16<<<dim3(32, 32), 256, 0, stream>>>(Wo, Wot, 2048, 2048);

  gemm_qkv256<<<dim3(16, 12), 512, 0, stream>>>(Xb, Wt, Qb, Kb, Vb);

  rope_inplace<<<1280, 256, 0, stream>>>(cosb, sinb, Qb, Kb);
  transpose_v<<<dim3(64, 8), 256, 0, stream>>>(Vb, Vt);

  attn_kernel<<<1024, 256, 0, stream>>>(Qb, Kb, Vt, amask, AO);

  gemm_bt<<<dim3(32, 16), 256, 0, stream>>>(AO, Wot, (float*)d_out, 4096, 2048, 2048);
}